// Round 1
// baseline (19.650 us; speedup 1.0000x reference)
//
#include <hip/hip_runtime.h>
#include <hip/hip_bf16.h>

// Problem constants (from setup_inputs): B=16, T=512, D=384, F=1, M=4096, mel_max_len=1536
constexpr int B    = 16;
constexpr int T    = 512;   // number of frames / durations per batch
constexpr int D    = 384;   // enc_out feature dim
constexpr int M    = 4096;  // pitch length
constexpr int MML  = 1536;  // mel_max_len
constexpr int V    = D / 4; // float4 per row = 96

constexpr int LCHUNK = 12;           // output rows per block
constexpr int CHUNKS = MML / LCHUNK; // 128

// Output layout (flat float32):
//   [0, B*MML*D)                      enc_rep
//   [B*MML*D, B*MML*D + B)            dec_lens (written as float)
//   [.. + B, .. + B + B*T)            pitch_avg (F=1)
constexpr long ENC_SZ    = (long)B * MML * D;   // 9437184
constexpr long DEC_OFF   = ENC_SZ;
constexpr long PITCH_OFF = ENC_SZ + B;

__global__ __launch_bounds__(256)
void fastpitch_fused(const float* __restrict__ enc,     // (B,T,D)
                     const int*   __restrict__ durs,    // (B,T)
                     const float* __restrict__ pitch,   // (B,1,M)
                     float*       __restrict__ out)
{
    __shared__ int s_cums[T + 1];   // cums[i] = sum durs[0..i-1]
    __shared__ int s_scan[256];
    __shared__ int s_tmap[LCHUNK];

    const int tid = threadIdx.x;
    const int b   = blockIdx.y;
    const int l0  = blockIdx.x * LCHUNK;

    // ---- 1. duration cumsum (pace==1.0 => reps == durs exactly) ----
    const int* db = durs + (size_t)b * T;
    int d0 = db[2 * tid];
    int d1 = db[2 * tid + 1];
    int p  = d0 + d1;

    s_scan[tid] = p;
    __syncthreads();
    #pragma unroll
    for (int off = 1; off < 256; off <<= 1) {
        int v   = s_scan[tid];
        int add = (tid >= off) ? s_scan[tid - off] : 0;
        __syncthreads();
        s_scan[tid] = v + add;
        __syncthreads();
    }
    int inc = s_scan[tid];      // inclusive pair-scan
    int e   = inc - p;          // exclusive prefix of pair
    s_cums[2 * tid]     = e;
    s_cums[2 * tid + 1] = e + d0;
    if (tid == 255) s_cums[T] = e + d0 + d1;
    __syncthreads();

    const int total = s_cums[T];

    // ---- 2. per-row frame index via binary search ----
    if (tid < LCHUNK) {
        int l  = l0 + tid;
        // largest idx in [0,T] with cums[idx] <= l  (cums[0]=0 <= l always)
        int lo = 0, hi = T;
        while (lo < hi) {
            int mid = (lo + hi + 1) >> 1;
            if (s_cums[mid] <= l) lo = mid; else hi = mid - 1;
        }
        s_tmap[tid] = (lo < T) ? lo : -1;   // lo==T  <=>  l >= total
    }
    __syncthreads();

    // ---- 3. row copy (float4, coalesced) ----
    {
        const float4* src = (const float4*)(enc + (size_t)b * T * D);
        float4*       dst = (float4*)(out + ((size_t)b * MML + l0) * D);
        const float4 zero = make_float4(0.f, 0.f, 0.f, 0.f);
        for (int idx = tid; idx < LCHUNK * V; idx += 256) {
            int ll = idx / V;
            int j  = idx - ll * V;
            int t  = s_tmap[ll];
            dst[(size_t)ll * V + j] = (t >= 0) ? src[(size_t)t * V + j] : zero;
        }
    }

    // ---- 4. dec_lens + pitch_avg (one block-column per batch) ----
    if (blockIdx.x == 0) {
        if (tid == 0) {
            int dl = total < MML ? total : MML;
            out[DEC_OFF + b] = (float)dl;
        }
        const float* pb = pitch + (size_t)b * M;   // F == 1
        for (int l = tid; l < T; l += 256) {
            int s  = s_cums[l];
            int en = s_cums[l + 1];
            float sum = 0.f;
            int   cnt = 0;
            for (int k = s; k < en; ++k) {
                float v = pb[k];
                sum += v;
                cnt += (v != 0.0f);
            }
            out[PITCH_OFF + (size_t)b * T + l] = cnt ? sum / (float)cnt : 0.0f;
        }
    }
}

extern "C" void kernel_launch(void* const* d_in, const int* in_sizes, int n_in,
                              void* d_out, int out_size, void* d_ws, size_t ws_size,
                              hipStream_t stream) {
    const float* enc   = (const float*)d_in[0];
    const int*   durs  = (const int*)d_in[1];
    const float* pitch = (const float*)d_in[2];
    float*       out   = (float*)d_out;

    dim3 grid(CHUNKS, B);
    fastpitch_fused<<<grid, 256, 0, stream>>>(enc, durs, pitch, out);
}